// Round 9
// baseline (263.734 us; speedup 1.0000x reference)
//
#include <hip/hip_runtime.h>
#include <hip/hip_cooperative_groups.h>
#include <math.h>

namespace cg = cooperative_groups;

// B=32, T=256, C=128, NEIGH=5, TOPK=4.
// ONE cooperative launch, 512 blocks x 256 threads (2 blocks/CU co-resident):
//  phase A (proj): units 768, strided. pf=norm(x@Wpf^T), ns=norm(x@Wns^T); v -> vt split
//  grid.sync()
//  phase B (gram): units 1024, strided (R8 BUG: covered only 512 -> b>=16 poison)
//  grid.sync()
//  phase C (fused): units 512, 1:1. rowmax conv + S + mask -> softmax -> MFMA PV

#define TT 256
#define CC 128

using bf16x8 = __attribute__((ext_vector_type(8))) short;
using f32x4  = __attribute__((ext_vector_type(4))) float;

__device__ __forceinline__ short bf_hi(float x) {
    unsigned u = __float_as_uint(x);
    return (short)((u + 0x7FFFu + ((u >> 16) & 1u)) >> 16);
}
__device__ __forceinline__ void bf_split(float x, short& h, short& l) {
    h = bf_hi(x);
    float hf = __uint_as_float(((unsigned)(unsigned short)h) << 16);
    l = bf_hi(x - hf);
}
__device__ __forceinline__ float max5(float a, float b, float c, float d, float e) {
    return fmaxf(fmaxf(fmaxf(a, b), fmaxf(c, d)), e);
}

struct LdsA {
    short Ah[32 * 40], Al[32 * 40];
    short Bh[128 * 40], Bl[128 * 40];
    float ssb[32][4];
};
struct LdsB {
    short Ah[64 * 40], Al[64 * 40], Bh[64 * 40], Bl[64 * 40];
};
struct LdsC {
    float Gs[20 * 256];
    float RM[20 * 256];
    short ATH[16 * 264], ATL[16 * 264];
    float RD[64], RMX[64];
};
union LdsU { LdsA a; LdsB b; LdsC c; };

__global__ __launch_bounds__(256, 2) void mega_kernel(
    const float* __restrict__ x, const int* __restrict__ radj,
    const int* __restrict__ inxs,
    const float* __restrict__ Wpf, const float* __restrict__ Wns,
    const float* __restrict__ Wv,
    const float* __restrict__ v_pf, const float* __restrict__ g_pf,
    const float* __restrict__ v_ns, const float* __restrict__ g_ns,
    float* __restrict__ pf, float* __restrict__ ns,
    short* __restrict__ vt_h, short* __restrict__ vt_l,
    float* __restrict__ G, float* __restrict__ S,
    float* __restrict__ out)
{
    cg::grid_group grid = cg::this_grid();
    __shared__ LdsU u;
    const int tid = threadIdx.x, bid = blockIdx.x;
    const int lane = tid & 63;
    const int quad = lane >> 4, lr = lane & 15;

    // ================= phase A: proj (768 units, strided) =======================
    for (int unit = bid; unit < 768; unit += 512) {
        const int row0 = (unit & 255) * 32;
        const int m = unit >> 8;
        const float* __restrict__ W = (m == 0) ? Wpf : (m == 1) ? Wns : Wv;
        const int wn = tid >> 6;
        f32x4 z4 = {0.f, 0.f, 0.f, 0.f};
        f32x4 acc[2][2] = {{z4, z4}, {z4, z4}};

        for (int k0 = 0; k0 < CC; k0 += 32) {
            __syncthreads();
            {
                int r = tid >> 3, q = (tid & 7) * 4;
                float4 a4 = *(const float4*)&x[(row0 + r) * CC + k0 + q];
                short4 h4, l4;
                bf_split(a4.x, h4.x, l4.x); bf_split(a4.y, h4.y, l4.y);
                bf_split(a4.z, h4.z, l4.z); bf_split(a4.w, h4.w, l4.w);
                *(short4*)&u.a.Ah[r * 40 + q] = h4; *(short4*)&u.a.Al[r * 40 + q] = l4;
            }
            for (int i = 0; i < 4; i++) {
                int flat = i * 256 + tid, r = flat >> 3, q = (flat & 7) * 4;
                float4 b4 = *(const float4*)&W[r * CC + k0 + q];
                short4 h4, l4;
                bf_split(b4.x, h4.x, l4.x); bf_split(b4.y, h4.y, l4.y);
                bf_split(b4.z, h4.z, l4.z); bf_split(b4.w, h4.w, l4.w);
                *(short4*)&u.a.Bh[r * 40 + q] = h4; *(short4*)&u.a.Bl[r * 40 + q] = l4;
            }
            __syncthreads();
            bf16x8 ah[2], al[2], bh[2], bl[2];
            for (int ra = 0; ra < 2; ra++) {
                int ar = (16 * ra + lr) * 40 + quad * 8;
                ah[ra] = *(bf16x8*)&u.a.Ah[ar];
                al[ra] = *(bf16x8*)&u.a.Al[ar];
            }
            for (int tn = 0; tn < 2; tn++) {
                int br = (32 * wn + 16 * tn + lr) * 40 + quad * 8;
                bh[tn] = *(bf16x8*)&u.a.Bh[br];
                bl[tn] = *(bf16x8*)&u.a.Bl[br];
            }
            for (int ra = 0; ra < 2; ra++)
                for (int tn = 0; tn < 2; tn++) {
                    acc[ra][tn] = __builtin_amdgcn_mfma_f32_16x16x32_bf16(ah[ra], bh[tn], acc[ra][tn], 0, 0, 0);
                    acc[ra][tn] = __builtin_amdgcn_mfma_f32_16x16x32_bf16(ah[ra], bl[tn], acc[ra][tn], 0, 0, 0);
                    acc[ra][tn] = __builtin_amdgcn_mfma_f32_16x16x32_bf16(al[ra], bh[tn], acc[ra][tn], 0, 0, 0);
                }
        }
        if (m < 2) {
            float* __restrict__ o = (m == 0) ? pf : ns;
            float ssp[2][4];
            for (int ra = 0; ra < 2; ra++)
                for (int reg = 0; reg < 4; reg++) {
                    float s = acc[ra][0][reg] * acc[ra][0][reg]
                            + acc[ra][1][reg] * acc[ra][1][reg];
                    for (int off = 1; off < 16; off <<= 1) s += __shfl_xor(s, off);
                    ssp[ra][reg] = s;
                }
            if (lr == 0)
                for (int ra = 0; ra < 2; ra++)
                    for (int reg = 0; reg < 4; reg++)
                        u.a.ssb[16 * ra + quad * 4 + reg][wn] = ssp[ra][reg];
            __syncthreads();
            for (int ra = 0; ra < 2; ra++)
                for (int reg = 0; reg < 4; reg++) {
                    int ml = 16 * ra + quad * 4 + reg;
                    float ss = u.a.ssb[ml][0] + u.a.ssb[ml][1] + u.a.ssb[ml][2] + u.a.ssb[ml][3];
                    float inv = 1.f / fmaxf(sqrtf(ss), 1e-12f);
                    int row = row0 + ml;
                    for (int tn = 0; tn < 2; tn++)
                        o[row * CC + 32 * wn + 16 * tn + lr] = acc[ra][tn][reg] * inv;
                }
        } else {
            for (int ra = 0; ra < 2; ra++) {
                int rowbase = row0 + 16 * ra + quad * 4;
                int b = rowbase >> 8, t0 = rowbase & 255;
                for (int tn = 0; tn < 2; tn++) {
                    int c = 32 * wn + 16 * tn + lr;
                    short4 h4, l4;
                    for (int reg = 0; reg < 4; reg++)
                        bf_split(acc[ra][tn][reg], ((short*)&h4)[reg], ((short*)&l4)[reg]);
                    size_t o = ((size_t)b * CC + c) * TT + t0;
                    *(short4*)&vt_h[o] = h4;
                    *(short4*)&vt_l[o] = l4;
                }
            }
        }
        __syncthreads();
    }
    grid.sync();

    // ================= phase B: gram (1024 units, strided — THE FIX) ============
    for (int unitB = bid; unitB < 1024; unitB += 512) {
        const int m0 = (unitB & 3) * 64, n0 = ((unitB >> 2) & 3) * 64;
        const int bz = unitB >> 4;
        const int b = bz >> 1, half = bz & 1;
        const float* __restrict__ Pb = pf + (size_t)b * TT * CC;
        const float* __restrict__ Nb = ns + (size_t)b * TT * CC;
        const float* __restrict__ Bsrc = half ? Nb : Pb;

        float w0 = 0.f, w1 = 0.f, w2 = 0.f, w3 = 0.f;
        int4 id0 = {0, 0, 0, 0}, id1 = {0, 0, 0, 0};
        if (half) {
            float n2 = v_ns[0]*v_ns[0] + v_ns[1]*v_ns[1] + v_ns[2]*v_ns[2] + v_ns[3]*v_ns[3];
            float sc = g_ns[0] / sqrtf(n2);
            w0 = sc*v_ns[0]; w1 = sc*v_ns[1]; w2 = sc*v_ns[2]; w3 = sc*v_ns[3];
            id0 = *(const int4*)&inxs[(b * TT + m0 + (tid >> 3)) * 4];
            id1 = *(const int4*)&inxs[(b * TT + m0 + 32 + (tid >> 3)) * 4];
        }
        const int wave = tid >> 6;
        const int wm = wave >> 1, wn = wave & 1;
        f32x4 z4 = {0.f, 0.f, 0.f, 0.f};
        f32x4 acc[2][2] = {{z4, z4}, {z4, z4}};

        for (int k0 = 0; k0 < CC; k0 += 32) {
            __syncthreads();
            for (int i = 0; i < 2; i++) {
                int flat = i * 256 + tid, r = flat >> 3, q = (flat & 7) * 4;
                float4 a4;
                if (!half) {
                    a4 = *(const float4*)&Pb[(m0 + r) * CC + k0 + q];
                } else {
                    int4 id = i ? id1 : id0;
                    float4 aa = *(const float4*)&Nb[id.x * CC + k0 + q];
                    float4 ab = *(const float4*)&Nb[id.y * CC + k0 + q];
                    float4 ac = *(const float4*)&Nb[id.z * CC + k0 + q];
                    float4 ad = *(const float4*)&Nb[id.w * CC + k0 + q];
                    a4.x = w0*aa.x + w1*ab.x + w2*ac.x + w3*ad.x;
                    a4.y = w0*aa.y + w1*ab.y + w2*ac.y + w3*ad.y;
                    a4.z = w0*aa.z + w1*ab.z + w2*ac.z + w3*ad.z;
                    a4.w = w0*aa.w + w1*ab.w + w2*ac.w + w3*ad.w;
                }
                float4 b4 = *(const float4*)&Bsrc[(n0 + r) * CC + k0 + q];
                short4 h4, l4;
                bf_split(a4.x, h4.x, l4.x); bf_split(a4.y, h4.y, l4.y);
                bf_split(a4.z, h4.z, l4.z); bf_split(a4.w, h4.w, l4.w);
                *(short4*)&u.b.Ah[r * 40 + q] = h4; *(short4*)&u.b.Al[r * 40 + q] = l4;
                bf_split(b4.x, h4.x, l4.x); bf_split(b4.y, h4.y, l4.y);
                bf_split(b4.z, h4.z, l4.z); bf_split(b4.w, h4.w, l4.w);
                *(short4*)&u.b.Bh[r * 40 + q] = h4; *(short4*)&u.b.Bl[r * 40 + q] = l4;
            }
            __syncthreads();
            bf16x8 bh[2], bl[2];
            for (int tn = 0; tn < 2; tn++) {
                int br = (32 * wn + 16 * tn + lr) * 40 + quad * 8;
                bh[tn] = *(bf16x8*)&u.b.Bh[br];
                bl[tn] = *(bf16x8*)&u.b.Bl[br];
            }
            for (int tm = 0; tm < 2; tm++) {
                int ar = (32 * wm + 16 * tm + lr) * 40 + quad * 8;
                bf16x8 ah = *(bf16x8*)&u.b.Ah[ar];
                bf16x8 al = *(bf16x8*)&u.b.Al[ar];
                for (int tn = 0; tn < 2; tn++) {
                    acc[tm][tn] = __builtin_amdgcn_mfma_f32_16x16x32_bf16(ah, bh[tn], acc[tm][tn], 0, 0, 0);
                    acc[tm][tn] = __builtin_amdgcn_mfma_f32_16x16x32_bf16(ah, bl[tn], acc[tm][tn], 0, 0, 0);
                    acc[tm][tn] = __builtin_amdgcn_mfma_f32_16x16x32_bf16(al, bh[tn], acc[tm][tn], 0, 0, 0);
                }
            }
        }
        float* __restrict__ Cb = (half ? S : G) + (size_t)b * TT * TT;
        for (int tm = 0; tm < 2; tm++)
            for (int tn = 0; tn < 2; tn++) {
                int rb = m0 + 32 * wm + 16 * tm + quad * 4;
                int cb = n0 + 32 * wn + 16 * tn + lr;
                for (int reg = 0; reg < 4; reg++)
                    Cb[(size_t)(rb + reg) * TT + cb] = acc[tm][tn][reg];
            }
        __syncthreads();
    }
    grid.sync();

    // ================= phase C: fused (512 units, 1:1) ==========================
    {
        const int xt = bid & 15, b = bid >> 4;
        const int x0 = xt * 16;
        const int rbase = min(max(x0 - 2, 0), TT - 5);
        for (int i = 0; i < 5; i++) {
            int flat = i * 256 + tid, ri = flat >> 6, q = (flat & 63) * 4;
            int r = min(rbase + ri, TT - 1);
            *(float4*)&u.c.Gs[ri * 256 + q] = *(const float4*)&G[(size_t)b * TT * TT + r * TT + q];
        }
        float n2 = 0.f;
        for (int i = 0; i < 5; i++) n2 += v_pf[i] * v_pf[i];
        float sc = g_pf[0] / sqrtf(n2);
        float wpf[5];
        for (int i = 0; i < 5; i++) wpf[i] = sc * v_pf[i];
        __syncthreads();
        for (int t = 0; t < 5; t++) {
            int task = t * 256 + tid;
            int i = task >> 6, g = task & 63;
            const float* row = &u.c.Gs[i * 256];
            float4 X = *(float4*)&row[4 * g];
            float m0_, m1_, m2_, m3_;
            if (g == 0) {
                float4 N = *(float4*)&row[4];
                float mx = fmaxf(fmaxf(X.x, X.y), fmaxf(X.z, X.w));
                m0_ = m1_ = m2_ = fmaxf(mx, N.x);
                m3_ = max5(X.y, X.z, X.w, N.x, N.y);
            } else if (g == 63) {
                float4 P = *(float4*)&row[248];
                m0_ = max5(P.z, P.w, X.x, X.y, X.z);
                float mx = fmaxf(fmaxf(X.x, X.y), fmaxf(X.z, X.w));
                m1_ = m2_ = m3_ = fmaxf(P.w, mx);
            } else {
                float4 P = *(float4*)&row[4 * g - 4];
                float4 N = *(float4*)&row[4 * g + 4];
                m0_ = max5(P.z, P.w, X.x, X.y, X.z);
                m1_ = max5(P.w, X.x, X.y, X.z, X.w);
                m2_ = max5(X.x, X.y, X.z, X.w, N.x);
                m3_ = max5(X.y, X.z, X.w, N.x, N.y);
            }
            float4 o4 = {m0_, m1_, m2_, m3_};
            *(float4*)&u.c.RM[i * 256 + 4 * g] = o4;
        }
        __syncthreads();
        const int y = tid;
        const size_t sb = (size_t)b * TT * TT;
        float lv[16];
        if (xt > 0 && xt < 15) {
            float rm[20];
            #pragma unroll
            for (int r = 0; r < 20; r++) rm[r] = u.c.RM[r * 256 + y];
            #pragma unroll
            for (int xi = 0; xi < 16; xi++) {
                float s = wpf[0] * rm[xi];
                #pragma unroll
                for (int i = 1; i < 5; i++) s = fmaf(wpf[i], rm[xi + i], s);
                lv[xi] = s;
            }
        } else {
            for (int xi = 0; xi < 16; xi++) {
                int sxr = min(max(x0 + xi - 2, 0), TT - 5) - rbase;
                float s = 0.f;
                for (int i = 0; i < 5; i++) s = fmaf(wpf[i], u.c.RM[(sxr + i) * 256 + y], s);
                lv[xi] = s;
            }
        }
        for (int xi = 0; xi < 16; xi++) {
            lv[xi] += S[sb + (x0 + xi) * TT + y];
            if (radj[sb + (x0 + xi) * TT + y] == 0) lv[xi] += -1e22f;
        }
        const int wv = tid >> 6;
        for (int xi = 0; xi < 16; xi++) {
            float v = lv[xi];
            for (int o = 32; o; o >>= 1) v = fmaxf(v, __shfl_xor(v, o));
            if (lane == 0) u.c.RMX[xi * 4 + wv] = v;
        }
        __syncthreads();
        for (int xi = 0; xi < 16; xi++) {
            float mx = fmaxf(fmaxf(u.c.RMX[xi * 4], u.c.RMX[xi * 4 + 1]),
                             fmaxf(u.c.RMX[xi * 4 + 2], u.c.RMX[xi * 4 + 3]));
            float e = __expf(lv[xi] - mx);
            short h, l;
            bf_split(e, h, l);
            u.c.ATH[xi * 264 + y] = h;
            u.c.ATL[xi * 264 + y] = l;
            for (int o = 32; o; o >>= 1) e += __shfl_xor(e, o);
            if (lane == 0) u.c.RD[xi * 4 + wv] = e;
        }
        __syncthreads();
        const int c0 = wv * 32;
        const short* __restrict__ vhb = vt_h + (size_t)b * CC * TT;
        const short* __restrict__ vlb = vt_l + (size_t)b * CC * TT;
        const int ar0 = (c0 + lr) * TT, ar1 = ar0 + 16 * TT;
        f32x4 z4 = {0.f, 0.f, 0.f, 0.f};
        f32x4 acc[2] = {z4, z4};
        #pragma unroll
        for (int k0 = 0; k0 < TT; k0 += 32) {
            int ko = k0 + quad * 8;
            bf16x8 bh = *(bf16x8*)&u.c.ATH[lr * 264 + ko];
            bf16x8 bl = *(bf16x8*)&u.c.ATL[lr * 264 + ko];
            bf16x8 a0h = *(const bf16x8*)&vhb[ar0 + ko];
            bf16x8 a0l = *(const bf16x8*)&vlb[ar0 + ko];
            bf16x8 a1h = *(const bf16x8*)&vhb[ar1 + ko];
            bf16x8 a1l = *(const bf16x8*)&vlb[ar1 + ko];
            acc[0] = __builtin_amdgcn_mfma_f32_16x16x32_bf16(a0h, bh, acc[0], 0, 0, 0);
            acc[0] = __builtin_amdgcn_mfma_f32_16x16x32_bf16(a0h, bl, acc[0], 0, 0, 0);
            acc[0] = __builtin_amdgcn_mfma_f32_16x16x32_bf16(a0l, bh, acc[0], 0, 0, 0);
            acc[1] = __builtin_amdgcn_mfma_f32_16x16x32_bf16(a1h, bh, acc[1], 0, 0, 0);
            acc[1] = __builtin_amdgcn_mfma_f32_16x16x32_bf16(a1h, bl, acc[1], 0, 0, 0);
            acc[1] = __builtin_amdgcn_mfma_f32_16x16x32_bf16(a1l, bh, acc[1], 0, 0, 0);
        }
        float sm = u.c.RD[lr * 4] + u.c.RD[lr * 4 + 1] + u.c.RD[lr * 4 + 2] + u.c.RD[lr * 4 + 3];
        float rinv = 1.f / sm;
        for (int tm = 0; tm < 2; tm++) {
            float4 r;
            r.x = acc[tm][0] * rinv; r.y = acc[tm][1] * rinv;
            r.z = acc[tm][2] * rinv; r.w = acc[tm][3] * rinv;
            *(float4*)&out[(size_t)b * TT * CC + (x0 + lr) * CC + c0 + 16 * tm + quad * 4] = r;
        }
    }
}

extern "C" void kernel_launch(void* const* d_in, const int* in_sizes, int n_in,
                              void* d_out, int out_size, void* d_ws, size_t ws_size,
                              hipStream_t stream) {
    const float* x    = (const float*)d_in[0];
    const int*   radj = (const int*)d_in[1];
    const int*   inxs = (const int*)d_in[2];
    const float* Wpf  = (const float*)d_in[3];
    const float* Wns  = (const float*)d_in[4];
    const float* Wv   = (const float*)d_in[5];
    const float* v_pf = (const float*)d_in[6];
    const float* g_pf = (const float*)d_in[7];
    const float* v_ns = (const float*)d_in[8];
    const float* g_ns = (const float*)d_in[9];
    float* out = (float*)d_out;

    char* base = (char*)d_ws;
    float* pf   = (float*)(base);                    // 4MB
    float* ns   = (float*)(base + (4u << 20));       // 4MB
    short* vt_h = (short*)(base + (8u << 20));       // 2MB
    short* vt_l = (short*)(base + (10u << 20));      // 2MB
    float* G    = (float*)(base + (12u << 20));      // 8MB
    float* S    = (float*)(base + (20u << 20));      // 8MB

    void* args[] = {
        (void*)&x, (void*)&radj, (void*)&inxs,
        (void*)&Wpf, (void*)&Wns, (void*)&Wv,
        (void*)&v_pf, (void*)&g_pf, (void*)&v_ns, (void*)&g_ns,
        (void*)&pf, (void*)&ns, (void*)&vt_h, (void*)&vt_l,
        (void*)&G, (void*)&S, (void*)&out
    };
    hipLaunchCooperativeKernel((const void*)mega_kernel, dim3(512), dim3(256),
                               args, 0, stream);
}

// Round 10
// 127.609 us; speedup vs baseline: 2.0667x; 2.0667x over previous
//
#include <hip/hip_runtime.h>
#include <math.h>

// B=32, T=256, C=128, NEIGH=5, TOPK=4.  Two launches:
// proj:     pf=norm(x@Wpf^T), ns=norm(x@Wns^T) -> SPLIT bf16 (h/l pairs);
//           v=x@Wv^T -> transposed split bf16 vt[c][t]
// bigfused: per (b, x-tile-16): G-rows(32x256) & S(16x256) via split-bf16 MFMA
//           (operands direct from L2 global splits; Q frags in registers;
//           NO barriers in the accumulate loop) -> LDS -> rowmax conv + mask
//           -> softmax -> MFMA PV -> out.  G/S never touch HBM.

#define TT 256
#define CC 128

using bf16x8 = __attribute__((ext_vector_type(8))) short;
using f32x4  = __attribute__((ext_vector_type(4))) float;

__device__ __forceinline__ short bf_hi(float x) {
    unsigned u = __float_as_uint(x);
    return (short)((u + 0x7FFFu + ((u >> 16) & 1u)) >> 16);
}
__device__ __forceinline__ void bf_split(float x, short& h, short& l) {
    h = bf_hi(x);
    float hf = __uint_as_float(((unsigned)(unsigned short)h) << 16);
    l = bf_hi(x - hf);
}
__device__ __forceinline__ float bf2f(short h) {
    return __uint_as_float(((unsigned)(unsigned short)h) << 16);
}
__device__ __forceinline__ float max5(float a, float b, float c, float d, float e) {
    return fmaxf(fmaxf(fmaxf(a, b), fmaxf(c, d)), e);
}

// ---- proj: 32 rows/block, one matrix per blockIdx.y, split-bf16 MFMA (R7 body;
// epilogue now stores pf/ns as split h/l shorts).
__global__ __launch_bounds__(256, 4) void proj_kernel(
    const float* __restrict__ x,
    const float* __restrict__ W0, const float* __restrict__ W1, const float* __restrict__ W2,
    short* __restrict__ pf_h, short* __restrict__ pf_l,
    short* __restrict__ ns_h, short* __restrict__ ns_l,
    short* __restrict__ vt_h, short* __restrict__ vt_l)
{
    __shared__ short Ah[32 * 40], Al[32 * 40];
    __shared__ short Bh[128 * 40], Bl[128 * 40];
    __shared__ float ssb[32][4];
    const int tid = threadIdx.x;
    const int row0 = blockIdx.x * 32;
    const int m = blockIdx.y;
    const float* __restrict__ W = (m == 0) ? W0 : (m == 1) ? W1 : W2;
    const int lane = tid & 63, wn = tid >> 6;
    const int quad = lane >> 4, lr = lane & 15;
    f32x4 z4 = {0.f, 0.f, 0.f, 0.f};
    f32x4 acc[2][2] = {{z4, z4}, {z4, z4}};

    for (int k0 = 0; k0 < CC; k0 += 32) {
        __syncthreads();
        {
            int r = tid >> 3, q = (tid & 7) * 4;
            float4 a4 = *(const float4*)&x[(row0 + r) * CC + k0 + q];
            short4 h4, l4;
            bf_split(a4.x, h4.x, l4.x); bf_split(a4.y, h4.y, l4.y);
            bf_split(a4.z, h4.z, l4.z); bf_split(a4.w, h4.w, l4.w);
            *(short4*)&Ah[r * 40 + q] = h4; *(short4*)&Al[r * 40 + q] = l4;
        }
        for (int i = 0; i < 4; i++) {
            int flat = i * 256 + tid, r = flat >> 3, q = (flat & 7) * 4;
            float4 b4 = *(const float4*)&W[r * CC + k0 + q];
            short4 h4, l4;
            bf_split(b4.x, h4.x, l4.x); bf_split(b4.y, h4.y, l4.y);
            bf_split(b4.z, h4.z, l4.z); bf_split(b4.w, h4.w, l4.w);
            *(short4*)&Bh[r * 40 + q] = h4; *(short4*)&Bl[r * 40 + q] = l4;
        }
        __syncthreads();
        bf16x8 ah[2], al[2], bh[2], bl[2];
        for (int ra = 0; ra < 2; ra++) {
            int ar = (16 * ra + lr) * 40 + quad * 8;
            ah[ra] = *(bf16x8*)&Ah[ar];
            al[ra] = *(bf16x8*)&Al[ar];
        }
        for (int tn = 0; tn < 2; tn++) {
            int br = (32 * wn + 16 * tn + lr) * 40 + quad * 8;
            bh[tn] = *(bf16x8*)&Bh[br];
            bl[tn] = *(bf16x8*)&Bl[br];
        }
        for (int ra = 0; ra < 2; ra++)
            for (int tn = 0; tn < 2; tn++) {
                acc[ra][tn] = __builtin_amdgcn_mfma_f32_16x16x32_bf16(ah[ra], bh[tn], acc[ra][tn], 0, 0, 0);
                acc[ra][tn] = __builtin_amdgcn_mfma_f32_16x16x32_bf16(ah[ra], bl[tn], acc[ra][tn], 0, 0, 0);
                acc[ra][tn] = __builtin_amdgcn_mfma_f32_16x16x32_bf16(al[ra], bh[tn], acc[ra][tn], 0, 0, 0);
            }
    }
    if (m < 2) {
        short* __restrict__ oh = (m == 0) ? pf_h : ns_h;
        short* __restrict__ ol = (m == 0) ? pf_l : ns_l;
        float ssp[2][4];
        for (int ra = 0; ra < 2; ra++)
            for (int reg = 0; reg < 4; reg++) {
                float s = acc[ra][0][reg] * acc[ra][0][reg]
                        + acc[ra][1][reg] * acc[ra][1][reg];
                for (int off = 1; off < 16; off <<= 1) s += __shfl_xor(s, off);
                ssp[ra][reg] = s;
            }
        if (lr == 0)
            for (int ra = 0; ra < 2; ra++)
                for (int reg = 0; reg < 4; reg++)
                    ssb[16 * ra + quad * 4 + reg][wn] = ssp[ra][reg];
        __syncthreads();
        for (int ra = 0; ra < 2; ra++)
            for (int reg = 0; reg < 4; reg++) {
                int ml = 16 * ra + quad * 4 + reg;
                float ss = ssb[ml][0] + ssb[ml][1] + ssb[ml][2] + ssb[ml][3];
                float inv = 1.f / fmaxf(sqrtf(ss), 1e-12f);
                int row = row0 + ml;
                for (int tn = 0; tn < 2; tn++) {
                    float v = acc[ra][tn][reg] * inv;
                    short h, l;
                    bf_split(v, h, l);
                    int idx = row * CC + 32 * wn + 16 * tn + lr;
                    oh[idx] = h; ol[idx] = l;
                }
            }
    } else {
        for (int ra = 0; ra < 2; ra++) {
            int rowbase = row0 + 16 * ra + quad * 4;
            int b = rowbase >> 8, t0 = rowbase & 255;
            for (int tn = 0; tn < 2; tn++) {
                int c = 32 * wn + 16 * tn + lr;
                short4 h4, l4;
                for (int reg = 0; reg < 4; reg++)
                    bf_split(acc[ra][tn][reg], ((short*)&h4)[reg], ((short*)&l4)[reg]);
                size_t o = ((size_t)b * CC + c) * TT + t0;
                *(short4*)&vt_h[o] = h4;
                *(short4*)&vt_l[o] = l4;
            }
        }
    }
}

// ---- bigfused: per (xt, b). LDS 57.3KB -> 2 blocks/CU.
// LDS float offsets: Gb[0,5120) 20x256 ; Sb[5120,9216) 16x256 ; RM[9216,14336) 20x256
// overlays into dead Gb: ATH[0,2112) ATL[2112,4224) RD[4224,4288) RMX[4288,4352)
__global__ __launch_bounds__(256, 2) void bigfused(
    const short* __restrict__ pf_h, const short* __restrict__ pf_l,
    const short* __restrict__ ns_h, const short* __restrict__ ns_l,
    const int* __restrict__ inxs, const float* __restrict__ v_ns,
    const float* __restrict__ g_ns, const int* __restrict__ radj,
    const float* __restrict__ v_pf, const float* __restrict__ g_pf,
    const short* __restrict__ vt_h, const short* __restrict__ vt_l,
    float* __restrict__ out)
{
    __shared__ float lds[14336];
    float* Gb  = &lds[0];
    float* Sb  = &lds[5120];
    float* RM  = &lds[9216];
    short* ATH = (short*)&lds[0];
    short* ATL = (short*)&lds[2112];
    float* RD  = &lds[4224];
    float* RMX = &lds[4288];

    const int tid = threadIdx.x;
    const int xt = blockIdx.x, b = blockIdx.y;
    const int x0 = xt * 16;
    const int rbase = min(max(x0 - 2, 0), TT - 5);
    const int a0 = min(rbase, TT - 32);
    const int d = rbase - a0;                      // 0 except xt=15 (d=14)
    const size_t nb = (size_t)b * TT * CC;
    const int lane = tid & 63, w = tid >> 6;
    const int quad = lane >> 4, lr = lane & 15;

    // ---- Q fragments in registers (no LDS, no barrier). Query row = x0+lr.
    bf16x8 aqh[4], aql[4];
    {
        float n2 = v_ns[0]*v_ns[0] + v_ns[1]*v_ns[1] + v_ns[2]*v_ns[2] + v_ns[3]*v_ns[3];
        float sc = g_ns[0] / sqrtf(n2);
        float wq[4] = {sc*v_ns[0], sc*v_ns[1], sc*v_ns[2], sc*v_ns[3]};
        int4 id = *(const int4*)&inxs[(b * TT + x0 + lr) * 4];
        int idl[4] = {id.x, id.y, id.z, id.w};
        float qv[4][8] = {};
        for (int n = 0; n < 4; n++) {
            const short* hb = &ns_h[nb + idl[n] * CC];
            const short* lb = &ns_l[nb + idl[n] * CC];
            for (int kk = 0; kk < 4; kk++) {
                int ko = kk * 32 + quad * 8;
                bf16x8 h8 = *(const bf16x8*)&hb[ko];
                bf16x8 l8 = *(const bf16x8*)&lb[ko];
                for (int e = 0; e < 8; e++)
                    qv[kk][e] = fmaf(wq[n], bf2f(h8[e]) + bf2f(l8[e]), qv[kk][e]);
            }
        }
        for (int kk = 0; kk < 4; kk++)
            for (int e = 0; e < 8; e++)
                bf_split(qv[kk][e], ((short*)&aqh[kk])[e], ((short*)&aql[kk])[e]);
    }

    // ---- MFMA accumulate: zero barriers. A rows a0+lr / a0+16+lr ; B rows c*64+w*16+lr.
    const int am0 = (a0 + lr) * CC, am1 = am0 + 16 * CC;
    int bcol[4];
    for (int c = 0; c < 4; c++) bcol[c] = (c * 64 + w * 16 + lr) * CC;
    f32x4 z4 = {0.f, 0.f, 0.f, 0.f};
    f32x4 accg[2][4], accs[4];
    for (int tm = 0; tm < 2; tm++) for (int c = 0; c < 4; c++) accg[tm][c] = z4;
    for (int c = 0; c < 4; c++) accs[c] = z4;

    #pragma unroll
    for (int kk = 0; kk < 4; kk++) {
        int ko = kk * 32 + quad * 8;
        bf16x8 a0h = *(const bf16x8*)&pf_h[nb + am0 + ko];
        bf16x8 a0l = *(const bf16x8*)&pf_l[nb + am0 + ko];
        bf16x8 a1h = *(const bf16x8*)&pf_h[nb + am1 + ko];
        bf16x8 a1l = *(const bf16x8*)&pf_l[nb + am1 + ko];
        #pragma unroll
        for (int c = 0; c < 4; c++) {
            bf16x8 bph = *(const bf16x8*)&pf_h[nb + bcol[c] + ko];
            bf16x8 bpl = *(const bf16x8*)&pf_l[nb + bcol[c] + ko];
            bf16x8 bnh = *(const bf16x8*)&ns_h[nb + bcol[c] + ko];
            bf16x8 bnl = *(const bf16x8*)&ns_l[nb + bcol[c] + ko];
            accg[0][c] = __builtin_amdgcn_mfma_f32_16x16x32_bf16(a0h, bph, accg[0][c], 0, 0, 0);
            accg[0][c] = __builtin_amdgcn_mfma_f32_16x16x32_bf16(a0h, bpl, accg[0][c], 0, 0, 0);
            accg[0][c] = __builtin_amdgcn_mfma_f32_16x16x32_bf16(a0l, bph, accg[0][c], 0, 0, 0);
            accg[1][c] = __builtin_amdgcn_mfma_f32_16x16x32_bf16(a1h, bph, accg[1][c], 0, 0, 0);
            accg[1][c] = __builtin_amdgcn_mfma_f32_16x16x32_bf16(a1h, bpl, accg[1][c], 0, 0, 0);
            accg[1][c] = __builtin_amdgcn_mfma_f32_16x16x32_bf16(a1l, bph, accg[1][c], 0, 0, 0);
            accs[c]    = __builtin_amdgcn_mfma_f32_16x16x32_bf16(aqh[kk], bnh, accs[c], 0, 0, 0);
            accs[c]    = __builtin_amdgcn_mfma_f32_16x16x32_bf16(aqh[kk], bnl, accs[c], 0, 0, 0);
            accs[c]    = __builtin_amdgcn_mfma_f32_16x16x32_bf16(aql[kk], bnh, accs[c], 0, 0, 0);
        }
    }
    // C layout: row = 16tm + quad*4 + reg (rel a0), col = c*64 + w*16 + lr.
    for (int tm = 0; tm < 2; tm++)
        for (int c = 0; c < 4; c++)
            for (int reg = 0; reg < 4; reg++) {
                int gr = 16 * tm + quad * 4 + reg;
                if (gr >= d && gr < d + 20)
                    Gb[(gr - d) * 256 + c * 64 + w * 16 + lr] = accg[tm][c][reg];
            }
    for (int c = 0; c < 4; c++)
        for (int reg = 0; reg < 4; reg++)
            Sb[(quad * 4 + reg) * 256 + c * 64 + w * 16 + lr] = accs[c][reg];
    __syncthreads();

    // ---- windowed row-max (vectorized), RM row i = rowmax of global row rbase+i
    for (int t = 0; t < 5; t++) {
        int task = t * 256 + tid;
        int i = task >> 6, g = task & 63;
        const float* row = &Gb[min(i, 31 - d) * 256];
        float4 X = *(float4*)&row[4 * g];
        float m0_, m1_, m2_, m3_;
        if (g == 0) {
            float4 N = *(float4*)&row[4];
            float mx = fmaxf(fmaxf(X.x, X.y), fmaxf(X.z, X.w));
            m0_ = m1_ = m2_ = fmaxf(mx, N.x);
            m3_ = max5(X.y, X.z, X.w, N.x, N.y);
        } else if (g == 63) {
            float4 P = *(float4*)&row[248];
            m0_ = max5(P.z, P.w, X.x, X.y, X.z);
            float mx = fmaxf(fmaxf(X.x, X.y), fmaxf(X.z, X.w));
            m1_ = m2_ = m3_ = fmaxf(P.w, mx);
        } else {
            float4 P = *(float4*)&row[4 * g - 4];
            float4 N = *(float4*)&row[4 * g + 4];
            m0_ = max5(P.z, P.w, X.x, X.y, X.z);
            m1_ = max5(P.w, X.x, X.y, X.z, X.w);
            m2_ = max5(X.x, X.y, X.z, X.w, N.x);
            m3_ = max5(X.y, X.z, X.w, N.x, N.y);
        }
        float4 o4 = {m0_, m1_, m2_, m3_};
        *(float4*)&RM[i * 256 + 4 * g] = o4;
    }
    __syncthreads();

    // ---- logits + softmax
    float n2p = 0.f;
    for (int i = 0; i < 5; i++) n2p += v_pf[i] * v_pf[i];
    float scp = g_pf[0] / sqrtf(n2p);
    float wpf[5];
    for (int i = 0; i < 5; i++) wpf[i] = scp * v_pf[i];
    const int y = tid;
    const size_t sb = (size_t)b * TT * TT;
    float lv[16];
    if (xt > 0 && xt < 15) {
        float rm[20];
        #pragma unroll
        for (int r = 0; r < 20; r++) rm[r] = RM[r * 256 + y];
        #pragma unroll
        for (int xi = 0; xi < 16; xi++) {
            float s = wpf[0] * rm[xi];
            #pragma unroll
            for (int i = 1; i < 5; i++) s = fmaf(wpf[i], rm[xi + i], s);
            lv[xi] = s;
        }
    } else {
        for (int xi = 0; xi < 16; xi++) {
            int sxr = min(max(x0 + xi - 2, 0), TT - 5) - rbase;
            float s = 0.f;
            for (int i = 0; i < 5; i++) s = fmaf(wpf[i], RM[(sxr + i) * 256 + y], s);
            lv[xi] = s;
        }
    }
    for (int xi = 0; xi < 16; xi++) {
        lv[xi] += Sb[xi * 256 + y];
        if (radj[sb + (x0 + xi) * TT + y] == 0) lv[xi] += -1e22f;
    }
    for (int xi = 0; xi < 16; xi++) {
        float v = lv[xi];
        for (int o = 32; o; o >>= 1) v = fmaxf(v, __shfl_xor(v, o));
        if (lane == 0) RMX[xi * 4 + w] = v;
    }
    __syncthreads();
    for (int xi = 0; xi < 16; xi++) {
        float mx = fmaxf(fmaxf(RMX[xi * 4], RMX[xi * 4 + 1]),
                         fmaxf(RMX[xi * 4 + 2], RMX[xi * 4 + 3]));
        float e = __expf(lv[xi] - mx);
        short h, l;
        bf_split(e, h, l);
        ATH[xi * 264 + y] = h;
        ATL[xi * 264 + y] = l;
        for (int o = 32; o; o >>= 1) e += __shfl_xor(e, o);
        if (lane == 0) RD[xi * 4 + w] = e;
    }
    __syncthreads();

    // ---- PV: out^T[c,q] tiles. A = vt (global split), B = attn (LDS split).
    const int c0 = w * 32;
    const short* __restrict__ vhb = vt_h + (size_t)b * CC * TT;
    const short* __restrict__ vlb = vt_l + (size_t)b * CC * TT;
    const int ar0 = (c0 + lr) * TT, ar1 = ar0 + 16 * TT;
    f32x4 acc2[2] = {z4, z4};
    #pragma unroll
    for (int k0 = 0; k0 < TT; k0 += 32) {
        int ko = k0 + quad * 8;
        bf16x8 bh = *(bf16x8*)&ATH[lr * 264 + ko];
        bf16x8 bl = *(bf16x8*)&ATL[lr * 264 + ko];
        bf16x8 a0h = *(const bf16x8*)&vhb[ar0 + ko];
        bf16x8 a0l = *(const bf16x8*)&vlb[ar0 + ko];
        bf16x8 a1h = *(const bf16x8*)&vhb[ar1 + ko];
        bf16x8 a1l = *(const bf16x8*)&vlb[ar1 + ko];
        acc2[0] = __builtin_amdgcn_mfma_f32_16x16x32_bf16(a0h, bh, acc2[0], 0, 0, 0);
        acc2[0] = __builtin_amdgcn_mfma_f32_16x16x32_bf16(a0h, bl, acc2[0], 0, 0, 0);
        acc2[0] = __builtin_amdgcn_mfma_f32_16x16x32_bf16(a0l, bh, acc2[0], 0, 0, 0);
        acc2[1] = __builtin_amdgcn_mfma_f32_16x16x32_bf16(a1h, bh, acc2[1], 0, 0, 0);
        acc2[1] = __builtin_amdgcn_mfma_f32_16x16x32_bf16(a1h, bl, acc2[1], 0, 0, 0);
        acc2[1] = __builtin_amdgcn_mfma_f32_16x16x32_bf16(a1l, bh, acc2[1], 0, 0, 0);
    }
    float sm = RD[lr * 4] + RD[lr * 4 + 1] + RD[lr * 4 + 2] + RD[lr * 4 + 3];
    float rinv = 1.f / sm;
    for (int tm = 0; tm < 2; tm++) {
        float4 r;
        r.x = acc2[tm][0] * rinv; r.y = acc2[tm][1] * rinv;
        r.z = acc2[tm][2] * rinv; r.w = acc2[tm][3] * rinv;
        *(float4*)&out[(size_t)b * TT * CC + (x0 + lr) * CC + c0 + 16 * tm + quad * 4] = r;
    }
}

extern "C" void kernel_launch(void* const* d_in, const int* in_sizes, int n_in,
                              void* d_out, int out_size, void* d_ws, size_t ws_size,
                              hipStream_t stream) {
    const float* x    = (const float*)d_in[0];
    const int*   radj = (const int*)d_in[1];
    const int*   inxs = (const int*)d_in[2];
    const float* Wpf  = (const float*)d_in[3];
    const float* Wns  = (const float*)d_in[4];
    const float* Wv   = (const float*)d_in[5];
    const float* v_pf = (const float*)d_in[6];
    const float* g_pf = (const float*)d_in[7];
    const float* v_ns = (const float*)d_in[8];
    const float* g_ns = (const float*)d_in[9];
    float* out = (float*)d_out;

    char* base = (char*)d_ws;
    short* pf_h = (short*)(base);                    // 2MB each
    short* pf_l = (short*)(base + (2u << 20));
    short* ns_h = (short*)(base + (4u << 20));
    short* ns_l = (short*)(base + (6u << 20));
    short* vt_h = (short*)(base + (8u << 20));
    short* vt_l = (short*)(base + (10u << 20));

    proj_kernel<<<dim3(256, 3), 256, 0, stream>>>(x, Wpf, Wns, Wv,
                                                  pf_h, pf_l, ns_h, ns_l, vt_h, vt_l);
    bigfused<<<dim3(16, 32), 256, 0, stream>>>(pf_h, pf_l, ns_h, ns_l,
                                               inxs, v_ns, g_ns, radj, v_pf, g_pf,
                                               vt_h, vt_l, out);
}